// Round 10
// baseline (103.778 us; speedup 1.0000x reference)
//
#include <hip/hip_runtime.h>
#include <hip/hip_bf16.h>

#define B_  8
#define T_  2048
#define C_  1024
#define H_  128

using f32x4  = __attribute__((ext_vector_type(4))) float;
using bf16x8 = __attribute__((ext_vector_type(8))) short;

__device__ __forceinline__ unsigned short f2bf(float f) {
    union { float f; unsigned u; } v; v.f = f;
    unsigned r = v.u + 0x7FFFu + ((v.u >> 16) & 1u);   // RNE
    return (unsigned short)(r >> 16);
}

// async global->LDS, 16 B per lane (dest = wave-uniform base + lane*16)
#define GLD16(gp, lp) \
    __builtin_amdgcn_global_load_lds((const __attribute__((address_space(1))) void*)(gp), \
                                     (__attribute__((address_space(3))) void*)(lp), 16, 0, 0)

// DPP cross-lane reduce within 16-lane rows (VALU-speed)
template<int C>
__device__ __forceinline__ float dppf(float v) {
    return __int_as_float(__builtin_amdgcn_update_dpp(0, __float_as_int(v), C, 0xF, 0xF, true));
}
#define DPPRED_MAX(v) { v = fmaxf(v, dppf<0xB1>(v)); v = fmaxf(v, dppf<0x4E>(v)); \
                        v = fmaxf(v, dppf<0x141>(v)); v = fmaxf(v, dppf<0x140>(v)); }
#define DPPRED_SUM(v) { v = v + dppf<0xB1>(v); v = v + dppf<0x4E>(v); \
                        v = v + dppf<0x141>(v); v = v + dppf<0x140>(v); }

// ---------------------------------------------------------------------------
// W{q,k,v} fp32 [1024][128] -> Wt bf16, K-CHUNK-MAJOR per (kt, col-half):
//   Wt[kt][ch][sub][colw][8]  (kt=k>>5, ch=col/192, sub=(k>>3)&3, colw=col%192)
// Each (kt,ch) panel = 12 KB contiguous = exact LDS image for global_load_lds.
// Wq pre-scaled by 1/32.
// ---------------------------------------------------------------------------
__global__ void wconv_kernel(const float* __restrict__ Wq,
                             const float* __restrict__ Wk,
                             const float* __restrict__ Wv,
                             unsigned short* __restrict__ Wt) {
    int id  = blockIdx.x * 256 + threadIdx.x;
    int col = id % 384;
    int k   = id / 384;
    const float* W = (col < 128) ? Wq : ((col < 256) ? Wk : Wv);
    float v = W[k * H_ + (col & 127)];
    if (col < 128) v *= 0.03125f;   // fold C^-0.5 into Wq (exact pow2)
    const int kt = k >> 5, sub = (k >> 3) & 3, e = k & 7;
    const int ch = col / 192, colw = col % 192;
    Wt[(size_t)kt * 12288 + ch * 6144 + (sub * 192 + colw) * 8 + e] = f2bf(v);
}

// ---------------------------------------------------------------------------
// Fused projection GEMM. Grid 512 (256 row-tiles x 2 col-halves) x 256 thr
// (4 waves; wave = 64r x 48c, acc[4][3]). BK=32, 32 steps, dbuf, 1 barrier/step.
// B staged via global_load_lds (linear 12 KB stream, k-chunk-major => all
// frag ds_read_b128 are 8-words/bank conflict-free, no padding needed).
// A (x fp32->bf16) staged through LDS once per block, k-chunk-major.
// ---------------------------------------------------------------------------
__launch_bounds__(256, 2)
__global__ void gemm_kernel(const float* __restrict__ x,
                            const unsigned short* __restrict__ Wt,
                            unsigned short* __restrict__ qb,
                            unsigned short* __restrict__ kb,
                            unsigned short* __restrict__ vT) {
    __shared__ __align__(16) unsigned short Bs[2][6144];  // [sub][192 colw][8]
    __shared__ __align__(16) unsigned short As[2][2048];  // [sub][64 row][8]

    const int tid  = threadIdx.x;
    const int wave = tid >> 6;
    const int lane = tid & 63;
    const int lo = lane & 15, hi = lane >> 4;
    const int rb = blockIdx.x >> 1;
    const int ch = blockIdx.x & 1;
    const int row0  = rb * 64;
    const int colw0 = wave * 48;               // within this 192-col half

    // A staging geometry: thread -> (row, k-quarter)
    const int arow = tid >> 2;                 // 0..63
    const int aq   = tid & 3;                  // 0..3 (k sub-chunk)
    const float* xsrc = x + (size_t)(row0 + arow) * C_ + aq * 8;

    f32x4 acc[4][3];
    #pragma unroll
    for (int rt = 0; rt < 4; ++rt)
        #pragma unroll
        for (int ct = 0; ct < 3; ++ct)
            acc[rt][ct] = f32x4{0.f, 0.f, 0.f, 0.f};

    // prologue: stage step 0
    {
        const unsigned short* g = Wt + (size_t)ch * 6144 + wave * 1536 + lane * 8;
        #pragma unroll
        for (int j = 0; j < 3; ++j)
            GLD16(g + j * 512, &Bs[0][wave * 1536 + j * 512]);
        float4 g0 = *(const float4*)(xsrc);
        float4 g1 = *(const float4*)(xsrc + 4);
        unsigned a0 = f2bf(g0.x) | ((unsigned)f2bf(g0.y) << 16);
        unsigned a1 = f2bf(g0.z) | ((unsigned)f2bf(g0.w) << 16);
        unsigned a2 = f2bf(g1.x) | ((unsigned)f2bf(g1.y) << 16);
        unsigned a3 = f2bf(g1.z) | ((unsigned)f2bf(g1.w) << 16);
        *(uint4*)&As[0][(aq * 64 + arow) * 8] = uint4{a0, a1, a2, a3};
    }
    __syncthreads();

    for (int k = 0; k < 32; ++k) {
        const int cur = k & 1;
        const int nxt = cur ^ 1;

        // issue step k+1 staging: B via global_load_lds, x to regs
        float4 g0, g1;
        if (k < 31) {
            const unsigned short* g = Wt + (size_t)(k + 1) * 12288 + ch * 6144
                                        + wave * 1536 + lane * 8;
            #pragma unroll
            for (int j = 0; j < 3; ++j)
                GLD16(g + j * 512, &Bs[nxt][wave * 1536 + j * 512]);
            g0 = *(const float4*)(xsrc + (k + 1) * 32);
            g1 = *(const float4*)(xsrc + (k + 1) * 32 + 4);
        }

        // fragments from LDS (k-chunk-major: conflict-free b128)
        bf16x8 af[4], bfr[3];
        #pragma unroll
        for (int rt = 0; rt < 4; ++rt)
            af[rt] = *(const bf16x8*)&As[cur][(hi * 64 + rt * 16 + lo) * 8];
        #pragma unroll
        for (int ct = 0; ct < 3; ++ct)
            bfr[ct] = *(const bf16x8*)&Bs[cur][(hi * 192 + colw0 + ct * 16 + lo) * 8];

        __builtin_amdgcn_s_setprio(1);
        #pragma unroll
        for (int ct = 0; ct < 3; ++ct)
            #pragma unroll
            for (int rt = 0; rt < 4; ++rt)
                acc[rt][ct] = __builtin_amdgcn_mfma_f32_16x16x32_bf16(af[rt], bfr[ct], acc[rt][ct], 0, 0, 0);
        __builtin_amdgcn_s_setprio(0);

        // convert + write A for step k+1
        if (k < 31) {
            unsigned a0 = f2bf(g0.x) | ((unsigned)f2bf(g0.y) << 16);
            unsigned a1 = f2bf(g0.z) | ((unsigned)f2bf(g0.w) << 16);
            unsigned a2 = f2bf(g1.x) | ((unsigned)f2bf(g1.y) << 16);
            unsigned a3 = f2bf(g1.z) | ((unsigned)f2bf(g1.w) << 16);
            *(uint4*)&As[nxt][(aq * 64 + arow) * 8] = uint4{a0, a1, a2, a3};
        }
        __syncthreads();   // drains gl_lds (vmcnt) + ds writes (lgkm)
    }

    // epilogue
    #pragma unroll
    for (int ct = 0; ct < 3; ++ct) {
        int col = ch * 192 + colw0 + ct * 16 + lo;
        int head = col >> 7;
        int h = col & 127;
        #pragma unroll
        for (int rt = 0; rt < 4; ++rt) {
            #pragma unroll
            for (int r = 0; r < 4; ++r) {
                int rg = row0 + rt * 16 + 4 * hi + r;
                unsigned short val = f2bf(acc[rt][ct][r]);
                if (head == 0)      qb[(size_t)rg * H_ + h] = val;
                else if (head == 1) kb[(size_t)rg * H_ + h] = val;
                else {
                    int b = rg >> 11, t = rg & (T_ - 1);
                    vT[((size_t)b * H_ + h) * T_ + t] = val;
                }
            }
        }
    }
}

// ---------------------------------------------------------------------------
// Flash pass 1 (best-known form, unchanged). Block = 8 waves (512 thr);
// QBLK=256; chunk = 256 kv = 4 x KV64 tiles. Grid 512, empties exit.
// ---------------------------------------------------------------------------
__launch_bounds__(512, 2)
__global__ void attn1_kernel(const unsigned short* __restrict__ qb,
                             const unsigned short* __restrict__ kb,
                             const unsigned short* __restrict__ vT,
                             float* __restrict__ Opart,
                             float* __restrict__ MLpart) {
    __shared__ unsigned short Ks[64 * 128];   // [kv][k], 16B chunks XOR-swizzled
    __shared__ unsigned short Vs[128 * 64];   // [h][kv], swizzled
    __shared__ unsigned short Ps[8][16][72];  // per-wave P transpose (2-pass)

    const int tid  = threadIdx.x;
    const int wave = tid >> 6;
    const int lane = tid & 63;
    const int lo = lane & 15, hi = lane >> 4;

    const int bid   = blockIdx.x;
    const int b     = bid & 7;
    const int chunk = (bid >> 3) & 7;
    const int qt    = 7 - (bid >> 6);
    if (chunk > qt) return;

    const int kv_begin = chunk << 8;
    const size_t bT = (size_t)b * T_;
    const int qrow0 = (qt << 8) + wave * 32;

    const int krow = tid >> 3, kcol = (tid & 7) * 2;
    const int vrow = tid >> 2, vcol = (tid & 3) * 2;
    const unsigned short* kgsrc = kb + (bT + krow) * H_ + kcol * 8;
    const unsigned short* vgsrc = vT + ((size_t)b * H_ + vrow) * T_ + vcol * 8;
    unsigned short* kdst0 = &Ks[krow * 128 + ((kcol ^ (krow & 7)) * 8)];
    unsigned short* kdst1 = &Ks[krow * 128 + (((kcol + 1) ^ (krow & 7)) * 8)];
    unsigned short* vdst0 = &Vs[vrow * 64 + ((vcol ^ (vrow & 7)) * 8)];
    unsigned short* vdst1 = &Vs[vrow * 64 + (((vcol + 1) ^ (vrow & 7)) * 8)];

    bf16x8 qf[2][4];
    #pragma unroll
    for (int q2 = 0; q2 < 2; ++q2)
        #pragma unroll
        for (int kc = 0; kc < 4; ++kc)
            qf[q2][kc] = *(const bf16x8*)(qb + (bT + qrow0 + 16 * q2 + lo) * H_ + kc * 32 + 8 * hi);

    float m[2][4], l[2][4];
    f32x4 o[2][8];
    #pragma unroll
    for (int q2 = 0; q2 < 2; ++q2)
        #pragma unroll
        for (int r = 0; r < 4; ++r) { m[q2][r] = -1e30f; l[q2][r] = 0.f; }
    #pragma unroll
    for (int q2 = 0; q2 < 2; ++q2)
        #pragma unroll
        for (int ct = 0; ct < 8; ++ct) o[q2][ct] = f32x4{0.f, 0.f, 0.f, 0.f};

    uint4 kr0 = *(const uint4*)(kgsrc + (size_t)kv_begin * H_);
    uint4 kr1 = *(const uint4*)(kgsrc + (size_t)kv_begin * H_ + 8);
    uint4 vr0 = *(const uint4*)(vgsrc + kv_begin);
    uint4 vr1 = *(const uint4*)(vgsrc + kv_begin + 8);

    for (int t = 0; t < 4; ++t) {
        const int kv0 = kv_begin + t * 64;
        __syncthreads();
        *(uint4*)kdst0 = kr0;
        *(uint4*)kdst1 = kr1;
        *(uint4*)vdst0 = vr0;
        *(uint4*)vdst1 = vr1;
        __syncthreads();
        if (t < 3) {
            const int kvn = kv0 + 64;
            kr0 = *(const uint4*)(kgsrc + (size_t)kvn * H_);
            kr1 = *(const uint4*)(kgsrc + (size_t)kvn * H_ + 8);
            vr0 = *(const uint4*)(vgsrc + kvn);
            vr1 = *(const uint4*)(vgsrc + kvn + 8);
        }
        if (kv0 > qrow0 + 31) continue;

        f32x4 s[2][4];
        #pragma unroll
        for (int q2 = 0; q2 < 2; ++q2)
            #pragma unroll
            for (int ct4 = 0; ct4 < 4; ++ct4) s[q2][ct4] = f32x4{0.f, 0.f, 0.f, 0.f};
        __builtin_amdgcn_s_setprio(1);
        #pragma unroll
        for (int ct4 = 0; ct4 < 4; ++ct4) {
            const int row = ct4 * 16 + lo;
            #pragma unroll
            for (int kc = 0; kc < 4; ++kc) {
                bf16x8 kf = *(const bf16x8*)&Ks[row * 128 + (((kc * 4 + hi) ^ (row & 7)) * 8)];
                s[0][ct4] = __builtin_amdgcn_mfma_f32_16x16x32_bf16(qf[0][kc], kf, s[0][ct4], 0, 0, 0);
                s[1][ct4] = __builtin_amdgcn_mfma_f32_16x16x32_bf16(qf[1][kc], kf, s[1][ct4], 0, 0, 0);
            }
        }
        __builtin_amdgcn_s_setprio(0);

        if (kv0 + 63 >= qrow0) {
            #pragma unroll
            for (int q2 = 0; q2 < 2; ++q2)
                #pragma unroll
                for (int ct4 = 0; ct4 < 4; ++ct4)
                    #pragma unroll
                    for (int r = 0; r < 4; ++r)
                        if (kv0 + ct4 * 16 + lo > qrow0 + 16 * q2 + 4 * hi + r)
                            s[q2][ct4][r] = -1e30f;
        }

        float alpha[2][4];
        #pragma unroll
        for (int q2 = 0; q2 < 2; ++q2) {
            #pragma unroll
            for (int r = 0; r < 4; ++r) {
                float pm = fmaxf(fmaxf(s[q2][0][r], s[q2][1][r]), fmaxf(s[q2][2][r], s[q2][3][r]));
                DPPRED_MAX(pm);
                float mn = fmaxf(m[q2][r], pm);
                alpha[q2][r] = __expf(m[q2][r] - mn);
                m[q2][r] = mn;
                #pragma unroll
                for (int ct4 = 0; ct4 < 4; ++ct4) s[q2][ct4][r] = __expf(s[q2][ct4][r] - mn);
                float rs = (s[q2][0][r] + s[q2][1][r]) + (s[q2][2][r] + s[q2][3][r]);
                DPPRED_SUM(rs);
                l[q2][r] = l[q2][r] * alpha[q2][r] + rs;
            }
        }
        #pragma unroll
        for (int q2 = 0; q2 < 2; ++q2)
            #pragma unroll
            for (int ct = 0; ct < 8; ++ct)
                #pragma unroll
                for (int r = 0; r < 4; ++r) o[q2][ct][r] *= alpha[q2][r];

        bf16x8 pa[2][2];
        #pragma unroll
        for (int q2 = 0; q2 < 2; ++q2) {
            #pragma unroll
            for (int ct4 = 0; ct4 < 4; ++ct4)
                #pragma unroll
                for (int r = 0; r < 4; ++r)
                    Ps[wave][4 * hi + r][ct4 * 16 + lo] = f2bf(s[q2][ct4][r]);
            pa[q2][0] = *(const bf16x8*)&Ps[wave][lo][8 * hi];
            pa[q2][1] = *(const bf16x8*)&Ps[wave][lo][32 + 8 * hi];
        }

        __builtin_amdgcn_s_setprio(1);
        #pragma unroll
        for (int ct = 0; ct < 8; ++ct) {
            const int row = ct * 16 + lo;
            #pragma unroll
            for (int half = 0; half < 2; ++half) {
                bf16x8 vf = *(const bf16x8*)&Vs[row * 64 + (((half * 4 + hi) ^ (row & 7)) * 8)];
                o[0][ct] = __builtin_amdgcn_mfma_f32_16x16x32_bf16(pa[0][half], vf, o[0][ct], 0, 0, 0);
                o[1][ct] = __builtin_amdgcn_mfma_f32_16x16x32_bf16(pa[1][half], vf, o[1][ct], 0, 0, 0);
            }
        }
        __builtin_amdgcn_s_setprio(0);
    }

    const int slot = b * 36 + ((qt * (qt + 1)) >> 1) + chunk;
    float* op = Opart + (size_t)slot * 32768 + (size_t)(wave * 32) * 128;
    #pragma unroll
    for (int q2 = 0; q2 < 2; ++q2)
        #pragma unroll
        for (int ct = 0; ct < 8; ++ct)
            #pragma unroll
            for (int r = 0; r < 4; ++r)
                op[(16 * q2 + 4 * hi + r) * 128 + ct * 16 + lo] = o[q2][ct][r];
    if (lo == 0) {
        #pragma unroll
        for (int q2 = 0; q2 < 2; ++q2)
            #pragma unroll
            for (int r = 0; r < 4; ++r) {
                int base = slot * 512 + (wave * 32 + 16 * q2 + 4 * hi + r) * 2;
                MLpart[base]     = m[q2][r];
                MLpart[base + 1] = l[q2][r];
            }
    }
}

// ---------------------------------------------------------------------------
// Flash pass 2: merge <= 8 chunk partials. 512 blocks x 128 thr.
// ---------------------------------------------------------------------------
__launch_bounds__(128)
__global__ void attn2_kernel(const float* __restrict__ Opart,
                             const float* __restrict__ MLpart,
                             float* __restrict__ out) {
    const int bid = blockIdx.x;
    const int b   = bid & 7;
    const int qt  = (bid >> 3) & 7;
    const int sub = bid >> 6;              // 0..7
    const int nch = qt + 1;
    const int slot0 = b * 36 + ((qt * (qt + 1)) >> 1);

    const int tid  = threadIdx.x;
    const int row  = tid >> 2;             // 0..31
    const int h0   = (tid & 3) * 32;
    const int srow = sub * 32 + row;       // row within slot

    float M = -1e30f;
    for (int c = 0; c < nch; ++c)
        M = fmaxf(M, MLpart[(slot0 + c) * 512 + srow * 2]);
    float L = 0.f;
    for (int c = 0; c < nch; ++c) {
        float mc = MLpart[(slot0 + c) * 512 + srow * 2];
        float lc = MLpart[(slot0 + c) * 512 + srow * 2 + 1];
        L += lc * __expf(mc - M);
    }

    float4 acc[8];
    #pragma unroll
    for (int j = 0; j < 8; ++j) acc[j] = float4{0.f, 0.f, 0.f, 0.f};
    for (int c = 0; c < nch; ++c) {
        float wc = __expf(MLpart[(slot0 + c) * 512 + srow * 2] - M);
        const float4* src = (const float4*)(Opart + (size_t)(slot0 + c) * 32768 + (size_t)srow * 128 + h0);
        #pragma unroll
        for (int j = 0; j < 8; ++j) {
            float4 v = src[j];
            acc[j].x += wc * v.x; acc[j].y += wc * v.y;
            acc[j].z += wc * v.z; acc[j].w += wc * v.w;
        }
    }
    float inv = 1.f / L;
    float4* dst = (float4*)(out + ((size_t)b * T_ + qt * 256 + srow) * H_ + h0);
    #pragma unroll
    for (int j = 0; j < 8; ++j) {
        float4 v = acc[j];
        dst[j] = float4{v.x * inv, v.y * inv, v.z * inv, v.w * inv};
    }
}

extern "C" void kernel_launch(void* const* d_in, const int* in_sizes, int n_in,
                              void* d_out, int out_size, void* d_ws, size_t ws_size,
                              hipStream_t stream) {
    const float* x  = (const float*)d_in[0];
    const float* Wq = (const float*)d_in[1];
    const float* Wk = (const float*)d_in[2];
    const float* Wv = (const float*)d_in[3];
    float* out = (float*)d_out;

    char* ws = (char*)d_ws;
    unsigned short* Wt  = (unsigned short*)ws;                          // 0.75 MB
    unsigned short* qbf = (unsigned short*)(ws + (size_t)384 * 1024 * 2);
    unsigned short* kbf = qbf + (size_t)B_ * T_ * H_;
    unsigned short* vTf = kbf + (size_t)B_ * T_ * H_;
    float* Opart  = (float*)(vTf + (size_t)B_ * T_ * H_);               // 36 MB
    float* MLpart = (float*)((char*)Opart + (size_t)288 * 32768 * 4);   // 0.56 MB

    wconv_kernel<<<(384 * 1024) / 256, 256, 0, stream>>>(Wq, Wk, Wv, Wt);
    gemm_kernel<<<B_ * T_ / 32, 256, 0, stream>>>(x, Wt, qbf, kbf, vTf);
    attn1_kernel<<<512, 512, 0, stream>>>(qbf, kbf, vTf, Opart, MLpart);
    attn2_kernel<<<512, 128, 0, stream>>>(Opart, MLpart, out);
}

// Round 11
// 92.602 us; speedup vs baseline: 1.1207x; 1.1207x over previous
//
#include <hip/hip_runtime.h>
#include <hip/hip_bf16.h>

#define B_  8
#define T_  2048
#define C_  1024
#define H_  128

using f32x4  = __attribute__((ext_vector_type(4))) float;
using bf16x8 = __attribute__((ext_vector_type(8))) short;

__device__ __forceinline__ unsigned short f2bf(float f) {
    union { float f; unsigned u; } v; v.f = f;
    unsigned r = v.u + 0x7FFFu + ((v.u >> 16) & 1u);   // RNE
    return (unsigned short)(r >> 16);
}

// async global->LDS, 16 B per lane (global src per-lane, LDS dest wave-uniform)
#define GLD16(gp, lp) \
    __builtin_amdgcn_global_load_lds((const __attribute__((address_space(1))) void*)(gp), \
                                     (__attribute__((address_space(3))) void*)(lp), 16, 0, 0)

// DPP cross-lane reduce within 16-lane rows (VALU-speed)
template<int C>
__device__ __forceinline__ float dppf(float v) {
    return __int_as_float(__builtin_amdgcn_update_dpp(0, __float_as_int(v), C, 0xF, 0xF, true));
}
#define DPPRED_MAX(v) { v = fmaxf(v, dppf<0xB1>(v)); v = fmaxf(v, dppf<0x4E>(v)); \
                        v = fmaxf(v, dppf<0x141>(v)); v = fmaxf(v, dppf<0x140>(v)); }
#define DPPRED_SUM(v) { v = v + dppf<0xB1>(v); v = v + dppf<0x4E>(v); \
                        v = v + dppf<0x141>(v); v = v + dppf<0x140>(v); }

// ---------------------------------------------------------------------------
// W{q,k,v} fp32 [1024][128] -> Wt bf16, K-CHUNK-MAJOR per kt:
//   Wt[kt][sub][col][8]   (kt=k>>5, sub=(k>>3)&3, e=k&7, col 0..383)
// Each kt panel = 24 KB contiguous = exact LDS image for global_load_lds.
// Wq pre-scaled by 1/32.
// ---------------------------------------------------------------------------
__global__ void wconv_kernel(const float* __restrict__ Wq,
                             const float* __restrict__ Wk,
                             const float* __restrict__ Wv,
                             unsigned short* __restrict__ Wt) {
    int id  = blockIdx.x * 256 + threadIdx.x;
    int col = id % 384;
    int k   = id / 384;
    const float* W = (col < 128) ? Wq : ((col < 256) ? Wk : Wv);
    float v = W[k * H_ + (col & 127)];
    if (col < 128) v *= 0.03125f;   // fold C^-0.5 into Wq (exact pow2)
    const int kt = k >> 5, sub = (k >> 3) & 3, e = k & 7;
    Wt[(size_t)kt * 12288 + (sub * 384 + col) * 8 + e] = f2bf(v);
}

// ---------------------------------------------------------------------------
// Fused projection GEMM. Grid 256 x 512 thr (8 waves; wave = 64r x 48c,
// acc[4][3]). Tile 64r x 384c (FULL width: B re-read factor 16384/64=256 ->
// 196 MB L2 total, x read ONCE). BK=32, 32 steps, dbuf, 1 barrier/step.
// B staged via global_load_lds (3 linear 1KB segs/wave); A fp32->bf16
// reg-converted with 2-deep x pipeline. k-chunk-major LDS: all frag
// ds_read_b128 2-lanes/bank (free).
// ---------------------------------------------------------------------------
__launch_bounds__(512, 2)
__global__ void gemm_kernel(const float* __restrict__ x,
                            const unsigned short* __restrict__ Wt,
                            unsigned short* __restrict__ qb,
                            unsigned short* __restrict__ kb,
                            unsigned short* __restrict__ vT) {
    __shared__ __align__(16) unsigned short Bs[2][12288];  // [sub][384 col][8]
    __shared__ __align__(16) unsigned short As[2][2048];   // [sub][64 row][8]

    const int tid  = threadIdx.x;
    const int wave = tid >> 6;
    const int lane = tid & 63;
    const int lo = lane & 15, hi = lane >> 4;
    const int row0 = blockIdx.x * 64;

    // A staging: thread -> (row, 4-float k-group)
    const int arow = tid >> 3;                 // 0..63
    const int aq   = tid & 7;                  // 0..7
    const float* xsrc = x + (size_t)(row0 + arow) * C_ + aq * 4;
    const int aoff = ((aq >> 1) * 64 + arow) * 8 + (aq & 1) * 4;

    // B staging: wave w covers segs 3w..3w+2 (1 KB each)
    const unsigned short* bsrc0 = Wt + (size_t)(wave * 3) * 512 + lane * 8;

    f32x4 acc[4][3];
    #pragma unroll
    for (int rt = 0; rt < 4; ++rt)
        #pragma unroll
        for (int ct = 0; ct < 3; ++ct)
            acc[rt][ct] = f32x4{0.f, 0.f, 0.f, 0.f};

    // prologue: stage step 0; load x for step 1
    {
        #pragma unroll
        for (int j = 0; j < 3; ++j)
            GLD16(bsrc0 + j * 512, &Bs[0][(wave * 3 + j) * 512]);
        float4 f = *(const float4*)xsrc;
        unsigned a0 = f2bf(f.x) | ((unsigned)f2bf(f.y) << 16);
        unsigned a1 = f2bf(f.z) | ((unsigned)f2bf(f.w) << 16);
        *(uint2*)&As[0][aoff] = uint2{a0, a1};
    }
    float4 h = *(const float4*)(xsrc + 32);
    __syncthreads();

    for (int k = 0; k < 32; ++k) {
        const int cur = k & 1, nxt = cur ^ 1;

        // issue step k+1 B staging (async, direct to LDS) + step k+2 x load
        if (k < 31) {
            const unsigned short* g = bsrc0 + (size_t)(k + 1) * 12288;
            GLD16(g,        &Bs[nxt][(wave * 3) * 512]);
            GLD16(g + 512,  &Bs[nxt][(wave * 3 + 1) * 512]);
            GLD16(g + 1024, &Bs[nxt][(wave * 3 + 2) * 512]);
        }
        float4 g2;
        if (k < 30) g2 = *(const float4*)(xsrc + (k + 2) * 32);

        // fragments from LDS (k-chunk-major: 2-lanes/bank, free)
        bf16x8 af[4], bfr[3];
        #pragma unroll
        for (int rt = 0; rt < 4; ++rt)
            af[rt] = *(const bf16x8*)&As[cur][(hi * 64 + rt * 16 + lo) * 8];
        #pragma unroll
        for (int ct = 0; ct < 3; ++ct)
            bfr[ct] = *(const bf16x8*)&Bs[cur][(hi * 384 + wave * 48 + ct * 16 + lo) * 8];

        __builtin_amdgcn_s_setprio(1);
        #pragma unroll
        for (int ct = 0; ct < 3; ++ct)
            #pragma unroll
            for (int rt = 0; rt < 4; ++rt)
                acc[rt][ct] = __builtin_amdgcn_mfma_f32_16x16x32_bf16(af[rt], bfr[ct], acc[rt][ct], 0, 0, 0);
        __builtin_amdgcn_s_setprio(0);

        // A convert+write for step k+1 (h loaded 2 steps ago: no wait)
        if (k < 31) {
            unsigned a0 = f2bf(h.x) | ((unsigned)f2bf(h.y) << 16);
            unsigned a1 = f2bf(h.z) | ((unsigned)f2bf(h.w) << 16);
            *(uint2*)&As[nxt][aoff] = uint2{a0, a1};
        }
        __syncthreads();   // drains gl_lds + ds writes; next buffer ready
        h = g2;
    }

    // epilogue
    #pragma unroll
    for (int ct = 0; ct < 3; ++ct) {
        int col = wave * 48 + ct * 16 + lo;
        int head = col >> 7;
        int h2 = col & 127;
        #pragma unroll
        for (int rt = 0; rt < 4; ++rt) {
            #pragma unroll
            for (int r = 0; r < 4; ++r) {
                int rg = row0 + rt * 16 + 4 * hi + r;
                unsigned short val = f2bf(acc[rt][ct][r]);
                if (head == 0)      qb[(size_t)rg * H_ + h2] = val;
                else if (head == 1) kb[(size_t)rg * H_ + h2] = val;
                else {
                    int b = rg >> 11, t = rg & (T_ - 1);
                    vT[((size_t)b * H_ + h2) * T_ + t] = val;
                }
            }
        }
    }
}

// ---------------------------------------------------------------------------
// Flash pass 1 (best-known form, unchanged). Block = 8 waves (512 thr);
// QBLK=256; chunk = 256 kv = 4 x KV64 tiles. Grid 512, empties exit.
// ---------------------------------------------------------------------------
__launch_bounds__(512, 2)
__global__ void attn1_kernel(const unsigned short* __restrict__ qb,
                             const unsigned short* __restrict__ kb,
                             const unsigned short* __restrict__ vT,
                             float* __restrict__ Opart,
                             float* __restrict__ MLpart) {
    __shared__ unsigned short Ks[64 * 128];   // [kv][k], 16B chunks XOR-swizzled
    __shared__ unsigned short Vs[128 * 64];   // [h][kv], swizzled
    __shared__ unsigned short Ps[8][16][72];  // per-wave P transpose (2-pass)

    const int tid  = threadIdx.x;
    const int wave = tid >> 6;
    const int lane = tid & 63;
    const int lo = lane & 15, hi = lane >> 4;

    const int bid   = blockIdx.x;
    const int b     = bid & 7;
    const int chunk = (bid >> 3) & 7;
    const int qt    = 7 - (bid >> 6);
    if (chunk > qt) return;

    const int kv_begin = chunk << 8;
    const size_t bT = (size_t)b * T_;
    const int qrow0 = (qt << 8) + wave * 32;

    const int krow = tid >> 3, kcol = (tid & 7) * 2;
    const int vrow = tid >> 2, vcol = (tid & 3) * 2;
    const unsigned short* kgsrc = kb + (bT + krow) * H_ + kcol * 8;
    const unsigned short* vgsrc = vT + ((size_t)b * H_ + vrow) * T_ + vcol * 8;
    unsigned short* kdst0 = &Ks[krow * 128 + ((kcol ^ (krow & 7)) * 8)];
    unsigned short* kdst1 = &Ks[krow * 128 + (((kcol + 1) ^ (krow & 7)) * 8)];
    unsigned short* vdst0 = &Vs[vrow * 64 + ((vcol ^ (vrow & 7)) * 8)];
    unsigned short* vdst1 = &Vs[vrow * 64 + (((vcol + 1) ^ (vrow & 7)) * 8)];

    bf16x8 qf[2][4];
    #pragma unroll
    for (int q2 = 0; q2 < 2; ++q2)
        #pragma unroll
        for (int kc = 0; kc < 4; ++kc)
            qf[q2][kc] = *(const bf16x8*)(qb + (bT + qrow0 + 16 * q2 + lo) * H_ + kc * 32 + 8 * hi);

    float m[2][4], l[2][4];
    f32x4 o[2][8];
    #pragma unroll
    for (int q2 = 0; q2 < 2; ++q2)
        #pragma unroll
        for (int r = 0; r < 4; ++r) { m[q2][r] = -1e30f; l[q2][r] = 0.f; }
    #pragma unroll
    for (int q2 = 0; q2 < 2; ++q2)
        #pragma unroll
        for (int ct = 0; ct < 8; ++ct) o[q2][ct] = f32x4{0.f, 0.f, 0.f, 0.f};

    uint4 kr0 = *(const uint4*)(kgsrc + (size_t)kv_begin * H_);
    uint4 kr1 = *(const uint4*)(kgsrc + (size_t)kv_begin * H_ + 8);
    uint4 vr0 = *(const uint4*)(vgsrc + kv_begin);
    uint4 vr1 = *(const uint4*)(vgsrc + kv_begin + 8);

    for (int t = 0; t < 4; ++t) {
        const int kv0 = kv_begin + t * 64;
        __syncthreads();
        *(uint4*)kdst0 = kr0;
        *(uint4*)kdst1 = kr1;
        *(uint4*)vdst0 = vr0;
        *(uint4*)vdst1 = vr1;
        __syncthreads();
        if (t < 3) {
            const int kvn = kv0 + 64;
            kr0 = *(const uint4*)(kgsrc + (size_t)kvn * H_);
            kr1 = *(const uint4*)(kgsrc + (size_t)kvn * H_ + 8);
            vr0 = *(const uint4*)(vgsrc + kvn);
            vr1 = *(const uint4*)(vgsrc + kvn + 8);
        }
        if (kv0 > qrow0 + 31) continue;

        f32x4 s[2][4];
        #pragma unroll
        for (int q2 = 0; q2 < 2; ++q2)
            #pragma unroll
            for (int ct4 = 0; ct4 < 4; ++ct4) s[q2][ct4] = f32x4{0.f, 0.f, 0.f, 0.f};
        __builtin_amdgcn_s_setprio(1);
        #pragma unroll
        for (int ct4 = 0; ct4 < 4; ++ct4) {
            const int row = ct4 * 16 + lo;
            #pragma unroll
            for (int kc = 0; kc < 4; ++kc) {
                bf16x8 kf = *(const bf16x8*)&Ks[row * 128 + (((kc * 4 + hi) ^ (row & 7)) * 8)];
                s[0][ct4] = __builtin_amdgcn_mfma_f32_16x16x32_bf16(qf[0][kc], kf, s[0][ct4], 0, 0, 0);
                s[1][ct4] = __builtin_amdgcn_mfma_f32_16x16x32_bf16(qf[1][kc], kf, s[1][ct4], 0, 0, 0);
            }
        }
        __builtin_amdgcn_s_setprio(0);

        if (kv0 + 63 >= qrow0) {
            #pragma unroll
            for (int q2 = 0; q2 < 2; ++q2)
                #pragma unroll
                for (int ct4 = 0; ct4 < 4; ++ct4)
                    #pragma unroll
                    for (int r = 0; r < 4; ++r)
                        if (kv0 + ct4 * 16 + lo > qrow0 + 16 * q2 + 4 * hi + r)
                            s[q2][ct4][r] = -1e30f;
        }

        float alpha[2][4];
        #pragma unroll
        for (int q2 = 0; q2 < 2; ++q2) {
            #pragma unroll
            for (int r = 0; r < 4; ++r) {
                float pm = fmaxf(fmaxf(s[q2][0][r], s[q2][1][r]), fmaxf(s[q2][2][r], s[q2][3][r]));
                DPPRED_MAX(pm);
                float mn = fmaxf(m[q2][r], pm);
                alpha[q2][r] = __expf(m[q2][r] - mn);
                m[q2][r] = mn;
                #pragma unroll
                for (int ct4 = 0; ct4 < 4; ++ct4) s[q2][ct4][r] = __expf(s[q2][ct4][r] - mn);
                float rs = (s[q2][0][r] + s[q2][1][r]) + (s[q2][2][r] + s[q2][3][r]);
                DPPRED_SUM(rs);
                l[q2][r] = l[q2][r] * alpha[q2][r] + rs;
            }
        }
        #pragma unroll
        for (int q2 = 0; q2 < 2; ++q2)
            #pragma unroll
            for (int ct = 0; ct < 8; ++ct)
                #pragma unroll
                for (int r = 0; r < 4; ++r) o[q2][ct][r] *= alpha[q2][r];

        bf16x8 pa[2][2];
        #pragma unroll
        for (int q2 = 0; q2 < 2; ++q2) {
            #pragma unroll
            for (int ct4 = 0; ct4 < 4; ++ct4)
                #pragma unroll
                for (int r = 0; r < 4; ++r)
                    Ps[wave][4 * hi + r][ct4 * 16 + lo] = f2bf(s[q2][ct4][r]);
            pa[q2][0] = *(const bf16x8*)&Ps[wave][lo][8 * hi];
            pa[q2][1] = *(const bf16x8*)&Ps[wave][lo][32 + 8 * hi];
        }

        __builtin_amdgcn_s_setprio(1);
        #pragma unroll
        for (int ct = 0; ct < 8; ++ct) {
            const int row = ct * 16 + lo;
            #pragma unroll
            for (int half = 0; half < 2; ++half) {
                bf16x8 vf = *(const bf16x8*)&Vs[row * 64 + (((half * 4 + hi) ^ (row & 7)) * 8)];
                o[0][ct] = __builtin_amdgcn_mfma_f32_16x16x32_bf16(pa[0][half], vf, o[0][ct], 0, 0, 0);
                o[1][ct] = __builtin_amdgcn_mfma_f32_16x16x32_bf16(pa[1][half], vf, o[1][ct], 0, 0, 0);
            }
        }
        __builtin_amdgcn_s_setprio(0);
    }

    const int slot = b * 36 + ((qt * (qt + 1)) >> 1) + chunk;
    float* op = Opart + (size_t)slot * 32768 + (size_t)(wave * 32) * 128;
    #pragma unroll
    for (int q2 = 0; q2 < 2; ++q2)
        #pragma unroll
        for (int ct = 0; ct < 8; ++ct)
            #pragma unroll
            for (int r = 0; r < 4; ++r)
                op[(16 * q2 + 4 * hi + r) * 128 + ct * 16 + lo] = o[q2][ct][r];
    if (lo == 0) {
        #pragma unroll
        for (int q2 = 0; q2 < 2; ++q2)
            #pragma unroll
            for (int r = 0; r < 4; ++r) {
                int base = slot * 512 + (wave * 32 + 16 * q2 + 4 * hi + r) * 2;
                MLpart[base]     = m[q2][r];
                MLpart[base + 1] = l[q2][r];
            }
    }
}

// ---------------------------------------------------------------------------
// Flash pass 2: merge <= 8 chunk partials. 512 blocks x 128 thr.
// ---------------------------------------------------------------------------
__launch_bounds__(128)
__global__ void attn2_kernel(const float* __restrict__ Opart,
                             const float* __restrict__ MLpart,
                             float* __restrict__ out) {
    const int bid = blockIdx.x;
    const int b   = bid & 7;
    const int qt  = (bid >> 3) & 7;
    const int sub = bid >> 6;              // 0..7
    const int nch = qt + 1;
    const int slot0 = b * 36 + ((qt * (qt + 1)) >> 1);

    const int tid  = threadIdx.x;
    const int row  = tid >> 2;             // 0..31
    const int h0   = (tid & 3) * 32;
    const int srow = sub * 32 + row;       // row within slot

    float M = -1e30f;
    for (int c = 0; c < nch; ++c)
        M = fmaxf(M, MLpart[(slot0 + c) * 512 + srow * 2]);
    float L = 0.f;
    for (int c = 0; c < nch; ++c) {
        float mc = MLpart[(slot0 + c) * 512 + srow * 2];
        float lc = MLpart[(slot0 + c) * 512 + srow * 2 + 1];
        L += lc * __expf(mc - M);
    }

    float4 acc[8];
    #pragma unroll
    for (int j = 0; j < 8; ++j) acc[j] = float4{0.f, 0.f, 0.f, 0.f};
    for (int c = 0; c < nch; ++c) {
        float wc = __expf(MLpart[(slot0 + c) * 512 + srow * 2] - M);
        const float4* src = (const float4*)(Opart + (size_t)(slot0 + c) * 32768 + (size_t)srow * 128 + h0);
        #pragma unroll
        for (int j = 0; j < 8; ++j) {
            float4 v = src[j];
            acc[j].x += wc * v.x; acc[j].y += wc * v.y;
            acc[j].z += wc * v.z; acc[j].w += wc * v.w;
        }
    }
    float inv = 1.f / L;
    float4* dst = (float4*)(out + ((size_t)b * T_ + qt * 256 + srow) * H_ + h0);
    #pragma unroll
    for (int j = 0; j < 8; ++j) {
        float4 v = acc[j];
        dst[j] = float4{v.x * inv, v.y * inv, v.z * inv, v.w * inv};
    }
}

extern "C" void kernel_launch(void* const* d_in, const int* in_sizes, int n_in,
                              void* d_out, int out_size, void* d_ws, size_t ws_size,
                              hipStream_t stream) {
    const float* x  = (const float*)d_in[0];
    const float* Wq = (const float*)d_in[1];
    const float* Wk = (const float*)d_in[2];
    const float* Wv = (const float*)d_in[3];
    float* out = (float*)d_out;

    char* ws = (char*)d_ws;
    unsigned short* Wt  = (unsigned short*)ws;                          // 0.75 MB
    unsigned short* qbf = (unsigned short*)(ws + (size_t)384 * 1024 * 2);
    unsigned short* kbf = qbf + (size_t)B_ * T_ * H_;
    unsigned short* vTf = kbf + (size_t)B_ * T_ * H_;
    float* Opart  = (float*)(vTf + (size_t)B_ * T_ * H_);               // 36 MB
    float* MLpart = (float*)((char*)Opart + (size_t)288 * 32768 * 4);   // 0.56 MB

    wconv_kernel<<<(384 * 1024) / 256, 256, 0, stream>>>(Wq, Wk, Wv, Wt);
    gemm_kernel<<<B_ * T_ / 64, 512, 0, stream>>>(x, Wt, qbf, kbf, vTf);
    attn1_kernel<<<512, 512, 0, stream>>>(qbf, kbf, vTf, Opart, MLpart);
    attn2_kernel<<<512, 128, 0, stream>>>(Opart, MLpart, out);
}

// Round 13
// 92.564 us; speedup vs baseline: 1.1211x; 1.0004x over previous
//
#include <hip/hip_runtime.h>
#include <hip/hip_bf16.h>

#define B_  8
#define T_  2048
#define C_  1024
#define H_  128

using f32x4  = __attribute__((ext_vector_type(4))) float;
using bf16x8 = __attribute__((ext_vector_type(8))) short;

__device__ __forceinline__ unsigned short f2bf(float f) {
    union { float f; unsigned u; } v; v.f = f;
    unsigned r = v.u + 0x7FFFu + ((v.u >> 16) & 1u);   // RNE
    return (unsigned short)(r >> 16);
}

// async global->LDS, 16 B per lane (global src per-lane, LDS dest wave-uniform)
#define GLD16(gp, lp) \
    __builtin_amdgcn_global_load_lds((const __attribute__((address_space(1))) void*)(gp), \
                                     (__attribute__((address_space(3))) void*)(lp), 16, 0, 0)

// DPP cross-lane reduce within 16-lane rows (VALU-speed)
template<int C>
__device__ __forceinline__ float dppf(float v) {
    return __int_as_float(__builtin_amdgcn_update_dpp(0, __float_as_int(v), C, 0xF, 0xF, true));
}
#define DPPRED_MAX(v) { v = fmaxf(v, dppf<0xB1>(v)); v = fmaxf(v, dppf<0x4E>(v)); \
                        v = fmaxf(v, dppf<0x141>(v)); v = fmaxf(v, dppf<0x140>(v)); }
#define DPPRED_SUM(v) { v = v + dppf<0xB1>(v); v = v + dppf<0x4E>(v); \
                        v = v + dppf<0x141>(v); v = v + dppf<0x140>(v); }

// ---------------------------------------------------------------------------
// W{q,k,v} fp32 [1024][128] -> Wt bf16, K-CHUNK-MAJOR per kt:
//   Wt[kt][sub][col][8]   (kt=k>>5, sub=(k>>3)&3, e=k&7, col 0..383)
// Each kt panel = 24 KB contiguous = exact LDS image for global_load_lds.
// Wq pre-scaled by 1/32.
// ---------------------------------------------------------------------------
__global__ void wconv_kernel(const float* __restrict__ Wq,
                             const float* __restrict__ Wk,
                             const float* __restrict__ Wv,
                             unsigned short* __restrict__ Wt) {
    int id  = blockIdx.x * 256 + threadIdx.x;
    int col = id % 384;
    int k   = id / 384;
    const float* W = (col < 128) ? Wq : ((col < 256) ? Wk : Wv);
    float v = W[k * H_ + (col & 127)];
    if (col < 128) v *= 0.03125f;   // fold C^-0.5 into Wq (exact pow2)
    const int kt = k >> 5, sub = (k >> 3) & 3, e = k & 7;
    Wt[(size_t)kt * 12288 + (sub * 384 + col) * 8 + e] = f2bf(v);
}

// ---------------------------------------------------------------------------
// Fused projection GEMM — counted-vmcnt pipeline (T3/T4), STRIDE-FIXED.
// Grid 256 x 512 thr (8 waves; wave = 64r x 48c). Tile 64x384, BK=32, 32 steps.
// B: gld16 (3 x 1KB segs/wave/step, seg = wave*3+j, stride 512 shorts),
//    triple-buffered, issued 2 steps ahead.
// A: x fp32 loaded 3 steps ahead (asm global_load_dwordx4, 1/wave/step),
//    converted+ds_written 1 step before use, triple-buffered.
// Barrier: s_waitcnt vmcnt(5) lgkmcnt(0) + raw s_barrier — retires B(t+1);
// x(t+2), B(t+2)x3, x(t+3) stay IN FLIGHT across the barrier.
// ---------------------------------------------------------------------------
__launch_bounds__(512)
__global__ void gemm_kernel(const float* __restrict__ x,
                            const unsigned short* __restrict__ Wt,
                            unsigned short* __restrict__ qb,
                            unsigned short* __restrict__ kb,
                            unsigned short* __restrict__ vT) {
    __shared__ __align__(16) unsigned short Bs[3][12288];  // [sub][384 col][8]
    __shared__ __align__(16) unsigned short As[3][2048];   // [sub][64 row][8]

    const int tid  = threadIdx.x;
    const int wave = tid >> 6;
    const int lane = tid & 63;
    const int lo = lane & 15, hi = lane >> 4;
    const int row0 = blockIdx.x * 64;

    // A staging: thread -> (row, 4-float k-group)
    const int arow = tid >> 3;                 // 0..63
    const int aq   = tid & 7;                  // 0..7
    const float* xsrc = x + (size_t)(row0 + arow) * C_ + aq * 4;
    const int aoff = ((aq >> 1) * 64 + arow) * 8 + (aq & 1) * 4;

    // B staging: wave w covers segs 3w..3w+2, 1 KB (=512 shorts) each
    const unsigned short* bsrc = Wt + (size_t)(wave * 3) * 512 + lane * 8;
    const int bdst = (wave * 3) * 512;

    f32x4 acc[4][3];
    #pragma unroll
    for (int rt = 0; rt < 4; ++rt)
        #pragma unroll
        for (int ct = 0; ct < 3; ++ct)
            acc[rt][ct] = f32x4{0.f, 0.f, 0.f, 0.f};

    f32x4 h0, hA, hB, hn;

    // ---- prologue: x(0); B(0); x(1); B(1); x(2)  (9 VMEM ops in flight) ----
    asm volatile("global_load_dwordx4 %0, %1, off" : "=v"(h0) : "v"(xsrc));
    #pragma unroll
    for (int j = 0; j < 3; ++j) GLD16(bsrc + j * 512, &Bs[0][bdst + j * 512]);
    asm volatile("global_load_dwordx4 %0, %1, off" : "=v"(hA) : "v"(xsrc + 32));
    #pragma unroll
    for (int j = 0; j < 3; ++j) GLD16(bsrc + 12288 + j * 512, &Bs[1][bdst + j * 512]);
    asm volatile("global_load_dwordx4 %0, %1, off" : "=v"(hB) : "v"(xsrc + 64));

    asm volatile("s_waitcnt vmcnt(8)" : "+v"(h0) :: "memory");   // x(0) landed
    {
        unsigned a0 = f2bf(h0.x) | ((unsigned)f2bf(h0.y) << 16);
        unsigned a1 = f2bf(h0.z) | ((unsigned)f2bf(h0.w) << 16);
        *(uint2*)&As[0][aoff] = uint2{a0, a1};
    }
    asm volatile("s_waitcnt vmcnt(5) lgkmcnt(0)" ::: "memory");  // B(0)+A(0) ready
    __builtin_amdgcn_sched_barrier(0);
    __builtin_amdgcn_s_barrier();
    __builtin_amdgcn_sched_barrier(0);

    int cur = 0, wr = 2, awr = 1;   // read buf, B-write buf (t+2), A-write buf (t+1)
    for (int t = 0; t < 32; ++t) {
        // issue B(t+2) [clamped] and x(t+3) [clamped] — uniform counts
        {
            const int ktI = (t + 2 < 31) ? t + 2 : 31;
            const unsigned short* g = bsrc + (size_t)ktI * 12288;
            GLD16(g,        &Bs[wr][bdst]);
            GLD16(g + 512,  &Bs[wr][bdst + 512]);
            GLD16(g + 1024, &Bs[wr][bdst + 1024]);
            const int kx = (t + 3 < 31) ? t + 3 : 31;
            asm volatile("global_load_dwordx4 %0, %1, off" : "=v"(hn) : "v"(xsrc + kx * 32));
        }

        // fragments from LDS (k-chunk-major: 2-lanes/bank, free)
        bf16x8 af[4], bfr[3];
        #pragma unroll
        for (int rt = 0; rt < 4; ++rt)
            af[rt] = *(const bf16x8*)&As[cur][(hi * 64 + rt * 16 + lo) * 8];
        #pragma unroll
        for (int ct = 0; ct < 3; ++ct)
            bfr[ct] = *(const bf16x8*)&Bs[cur][(hi * 384 + wave * 48 + ct * 16 + lo) * 8];

        __builtin_amdgcn_s_setprio(1);
        #pragma unroll
        for (int ct = 0; ct < 3; ++ct)
            #pragma unroll
            for (int rt = 0; rt < 4; ++rt)
                acc[rt][ct] = __builtin_amdgcn_mfma_f32_16x16x32_bf16(af[rt], bfr[ct], acc[rt][ct], 0, 0, 0);
        __builtin_amdgcn_s_setprio(0);

        // convert + write A(t+1): hA loaded 3 steps ago (HBM latency covered)
        asm volatile("s_waitcnt vmcnt(8)" : "+v"(hA) :: "memory");
        {
            unsigned a0 = f2bf(hA.x) | ((unsigned)f2bf(hA.y) << 16);
            unsigned a1 = f2bf(hA.z) | ((unsigned)f2bf(hA.w) << 16);
            *(uint2*)&As[awr][aoff] = uint2{a0, a1};
        }
        hA = hB; hB = hn;

        // counted barrier: retire B(t+1) only; keep x(t+2),B(t+2)x3,x(t+3) flying
        asm volatile("s_waitcnt vmcnt(5) lgkmcnt(0)" ::: "memory");
        __builtin_amdgcn_sched_barrier(0);
        __builtin_amdgcn_s_barrier();
        __builtin_amdgcn_sched_barrier(0);

        cur = (cur == 2) ? 0 : cur + 1;
        wr  = (wr  == 2) ? 0 : wr  + 1;
        awr = (awr == 2) ? 0 : awr + 1;
    }

    // epilogue
    #pragma unroll
    for (int ct = 0; ct < 3; ++ct) {
        int col = wave * 48 + ct * 16 + lo;
        int head = col >> 7;
        int h2 = col & 127;
        #pragma unroll
        for (int rt = 0; rt < 4; ++rt) {
            #pragma unroll
            for (int r = 0; r < 4; ++r) {
                int rg = row0 + rt * 16 + 4 * hi + r;
                unsigned short val = f2bf(acc[rt][ct][r]);
                if (head == 0)      qb[(size_t)rg * H_ + h2] = val;
                else if (head == 1) kb[(size_t)rg * H_ + h2] = val;
                else {
                    int b = rg >> 11, t = rg & (T_ - 1);
                    vT[((size_t)b * H_ + h2) * T_ + t] = val;
                }
            }
        }
    }
}

// ---------------------------------------------------------------------------
// Flash pass 1 (best-known form, unchanged). Block = 8 waves (512 thr);
// QBLK=256; chunk = 256 kv = 4 x KV64 tiles. Grid 512, empties exit.
// ---------------------------------------------------------------------------
__launch_bounds__(512, 2)
__global__ void attn1_kernel(const unsigned short* __restrict__ qb,
                             const unsigned short* __restrict__ kb,
                             const unsigned short* __restrict__ vT,
                             float* __restrict__ Opart,
                             float* __restrict__ MLpart) {
    __shared__ unsigned short Ks[64 * 128];   // [kv][k], 16B chunks XOR-swizzled
    __shared__ unsigned short Vs[128 * 64];   // [h][kv], swizzled
    __shared__ unsigned short Ps[8][16][72];  // per-wave P transpose (2-pass)

    const int tid  = threadIdx.x;
    const int wave = tid >> 6;
    const int lane = tid & 63;
    const int lo = lane & 15, hi = lane >> 4;

    const int bid   = blockIdx.x;
    const int b     = bid & 7;
    const int chunk = (bid >> 3) & 7;
    const int qt    = 7 - (bid >> 6);
    if (chunk > qt) return;

    const int kv_begin = chunk << 8;
    const size_t bT = (size_t)b * T_;
    const int qrow0 = (qt << 8) + wave * 32;

    const int krow = tid >> 3, kcol = (tid & 7) * 2;
    const int vrow = tid >> 2, vcol = (tid & 3) * 2;
    const unsigned short* kgsrc = kb + (bT + krow) * H_ + kcol * 8;
    const unsigned short* vgsrc = vT + ((size_t)b * H_ + vrow) * T_ + vcol * 8;
    unsigned short* kdst0 = &Ks[krow * 128 + ((kcol ^ (krow & 7)) * 8)];
    unsigned short* kdst1 = &Ks[krow * 128 + (((kcol + 1) ^ (krow & 7)) * 8)];
    unsigned short* vdst0 = &Vs[vrow * 64 + ((vcol ^ (vrow & 7)) * 8)];
    unsigned short* vdst1 = &Vs[vrow * 64 + (((vcol + 1) ^ (vrow & 7)) * 8)];

    bf16x8 qf[2][4];
    #pragma unroll
    for (int q2 = 0; q2 < 2; ++q2)
        #pragma unroll
        for (int kc = 0; kc < 4; ++kc)
            qf[q2][kc] = *(const bf16x8*)(qb + (bT + qrow0 + 16 * q2 + lo) * H_ + kc * 32 + 8 * hi);

    float m[2][4], l[2][4];
    f32x4 o[2][8];
    #pragma unroll
    for (int q2 = 0; q2 < 2; ++q2)
        #pragma unroll
        for (int r = 0; r < 4; ++r) { m[q2][r] = -1e30f; l[q2][r] = 0.f; }
    #pragma unroll
    for (int q2 = 0; q2 < 2; ++q2)
        #pragma unroll
        for (int ct = 0; ct < 8; ++ct) o[q2][ct] = f32x4{0.f, 0.f, 0.f, 0.f};

    uint4 kr0 = *(const uint4*)(kgsrc + (size_t)kv_begin * H_);
    uint4 kr1 = *(const uint4*)(kgsrc + (size_t)kv_begin * H_ + 8);
    uint4 vr0 = *(const uint4*)(vgsrc + kv_begin);
    uint4 vr1 = *(const uint4*)(vgsrc + kv_begin + 8);

    for (int t = 0; t < 4; ++t) {
        const int kv0 = kv_begin + t * 64;
        __syncthreads();
        *(uint4*)kdst0 = kr0;
        *(uint4*)kdst1 = kr1;
        *(uint4*)vdst0 = vr0;
        *(uint4*)vdst1 = vr1;
        __syncthreads();
        if (t < 3) {
            const int kvn = kv0 + 64;
            kr0 = *(const uint4*)(kgsrc + (size_t)kvn * H_);
            kr1 = *(const uint4*)(kgsrc + (size_t)kvn * H_ + 8);
            vr0 = *(const uint4*)(vgsrc + kvn);
            vr1 = *(const uint4*)(vgsrc + kvn + 8);
        }
        if (kv0 > qrow0 + 31) continue;

        f32x4 s[2][4];
        #pragma unroll
        for (int q2 = 0; q2 < 2; ++q2)
            #pragma unroll
            for (int ct4 = 0; ct4 < 4; ++ct4) s[q2][ct4] = f32x4{0.f, 0.f, 0.f, 0.f};
        __builtin_amdgcn_s_setprio(1);
        #pragma unroll
        for (int ct4 = 0; ct4 < 4; ++ct4) {
            const int row = ct4 * 16 + lo;
            #pragma unroll
            for (int kc = 0; kc < 4; ++kc) {
                bf16x8 kf = *(const bf16x8*)&Ks[row * 128 + (((kc * 4 + hi) ^ (row & 7)) * 8)];
                s[0][ct4] = __builtin_amdgcn_mfma_f32_16x16x32_bf16(qf[0][kc], kf, s[0][ct4], 0, 0, 0);
                s[1][ct4] = __builtin_amdgcn_mfma_f32_16x16x32_bf16(qf[1][kc], kf, s[1][ct4], 0, 0, 0);
            }
        }
        __builtin_amdgcn_s_setprio(0);

        if (kv0 + 63 >= qrow0) {
            #pragma unroll
            for (int q2 = 0; q2 < 2; ++q2)
                #pragma unroll
                for (int ct4 = 0; ct4 < 4; ++ct4)
                    #pragma unroll
                    for (int r = 0; r < 4; ++r)
                        if (kv0 + ct4 * 16 + lo > qrow0 + 16 * q2 + 4 * hi + r)
                            s[q2][ct4][r] = -1e30f;
        }

        float alpha[2][4];
        #pragma unroll
        for (int q2 = 0; q2 < 2; ++q2) {
            #pragma unroll
            for (int r = 0; r < 4; ++r) {
                float pm = fmaxf(fmaxf(s[q2][0][r], s[q2][1][r]), fmaxf(s[q2][2][r], s[q2][3][r]));
                DPPRED_MAX(pm);
                float mn = fmaxf(m[q2][r], pm);
                alpha[q2][r] = __expf(m[q2][r] - mn);
                m[q2][r] = mn;
                #pragma unroll
                for (int ct4 = 0; ct4 < 4; ++ct4) s[q2][ct4][r] = __expf(s[q2][ct4][r] - mn);
                float rs = (s[q2][0][r] + s[q2][1][r]) + (s[q2][2][r] + s[q2][3][r]);
                DPPRED_SUM(rs);
                l[q2][r] = l[q2][r] * alpha[q2][r] + rs;
            }
        }
        #pragma unroll
        for (int q2 = 0; q2 < 2; ++q2)
            #pragma unroll
            for (int ct = 0; ct < 8; ++ct)
                #pragma unroll
                for (int r = 0; r < 4; ++r) o[q2][ct][r] *= alpha[q2][r];

        bf16x8 pa[2][2];
        #pragma unroll
        for (int q2 = 0; q2 < 2; ++q2) {
            #pragma unroll
            for (int ct4 = 0; ct4 < 4; ++ct4)
                #pragma unroll
                for (int r = 0; r < 4; ++r)
                    Ps[wave][4 * hi + r][ct4 * 16 + lo] = f2bf(s[q2][ct4][r]);
            pa[q2][0] = *(const bf16x8*)&Ps[wave][lo][8 * hi];
            pa[q2][1] = *(const bf16x8*)&Ps[wave][lo][32 + 8 * hi];
        }

        __builtin_amdgcn_s_setprio(1);
        #pragma unroll
        for (int ct = 0; ct < 8; ++ct) {
            const int row = ct * 16 + lo;
            #pragma unroll
            for (int half = 0; half < 2; ++half) {
                bf16x8 vf = *(const bf16x8*)&Vs[row * 64 + (((half * 4 + hi) ^ (row & 7)) * 8)];
                o[0][ct] = __builtin_amdgcn_mfma_f32_16x16x32_bf16(pa[0][half], vf, o[0][ct], 0, 0, 0);
                o[1][ct] = __builtin_amdgcn_mfma_f32_16x16x32_bf16(pa[1][half], vf, o[1][ct], 0, 0, 0);
            }
        }
        __builtin_amdgcn_s_setprio(0);
    }

    const int slot = b * 36 + ((qt * (qt + 1)) >> 1) + chunk;
    float* op = Opart + (size_t)slot * 32768 + (size_t)(wave * 32) * 128;
    #pragma unroll
    for (int q2 = 0; q2 < 2; ++q2)
        #pragma unroll
        for (int ct = 0; ct < 8; ++ct)
            #pragma unroll
            for (int r = 0; r < 4; ++r)
                op[(16 * q2 + 4 * hi + r) * 128 + ct * 16 + lo] = o[q2][ct][r];
    if (lo == 0) {
        #pragma unroll
        for (int q2 = 0; q2 < 2; ++q2)
            #pragma unroll
            for (int r = 0; r < 4; ++r) {
                int base = slot * 512 + (wave * 32 + 16 * q2 + 4 * hi + r) * 2;
                MLpart[base]     = m[q2][r];
                MLpart[base + 1] = l[q2][r];
            }
    }
}

// ---------------------------------------------------------------------------
// Flash pass 2: merge <= 8 chunk partials. 512 blocks x 128 thr.
// ---------------------------------------------------------------------------
__launch_bounds__(128)
__global__ void attn2_kernel(const float* __restrict__ Opart,
                             const float* __restrict__ MLpart,
                             float* __restrict__ out) {
    const int bid = blockIdx.x;
    const int b   = bid & 7;
    const int qt  = (bid >> 3) & 7;
    const int sub = bid >> 6;              // 0..7
    const int nch = qt + 1;
    const int slot0 = b * 36 + ((qt * (qt + 1)) >> 1);

    const int tid  = threadIdx.x;
    const int row  = tid >> 2;             // 0..31
    const int h0   = (tid & 3) * 32;
    const int srow = sub * 32 + row;       // row within slot

    float M = -1e30f;
    for (int c = 0; c < nch; ++c)
        M = fmaxf(M, MLpart[(slot0 + c) * 512 + srow * 2]);
    float L = 0.f;
    for (int c = 0; c < nch; ++c) {
        float mc = MLpart[(slot0 + c) * 512 + srow * 2];
        float lc = MLpart[(slot0 + c) * 512 + srow * 2 + 1];
        L += lc * __expf(mc - M);
    }

    float4 acc[8];
    #pragma unroll
    for (int j = 0; j < 8; ++j) acc[j] = float4{0.f, 0.f, 0.f, 0.f};
    for (int c = 0; c < nch; ++c) {
        float wc = __expf(MLpart[(slot0 + c) * 512 + srow * 2] - M);
        const float4* src = (const float4*)(Opart + (size_t)(slot0 + c) * 32768 + (size_t)srow * 128 + h0);
        #pragma unroll
        for (int j = 0; j < 8; ++j) {
            float4 v = src[j];
            acc[j].x += wc * v.x; acc[j].y += wc * v.y;
            acc[j].z += wc * v.z; acc[j].w += wc * v.w;
        }
    }
    float inv = 1.f / L;
    float4* dst = (float4*)(out + ((size_t)b * T_ + qt * 256 + srow) * H_ + h0);
    #pragma unroll
    for (int j = 0; j < 8; ++j) {
        float4 v = acc[j];
        dst[j] = float4{v.x * inv, v.y * inv, v.z * inv, v.w * inv};
    }
}

extern "C" void kernel_launch(void* const* d_in, const int* in_sizes, int n_in,
                              void* d_out, int out_size, void* d_ws, size_t ws_size,
                              hipStream_t stream) {
    const float* x  = (const float*)d_in[0];
    const float* Wq = (const float*)d_in[1];
    const float* Wk = (const float*)d_in[2];
    const float* Wv = (const float*)d_in[3];
    float* out = (float*)d_out;

    char* ws = (char*)d_ws;
    unsigned short* Wt  = (unsigned short*)ws;                          // 0.75 MB
    unsigned short* qbf = (unsigned short*)(ws + (size_t)384 * 1024 * 2);
    unsigned short* kbf = qbf + (size_t)B_ * T_ * H_;
    unsigned short* vTf = kbf + (size_t)B_ * T_ * H_;
    float* Opart  = (float*)(vTf + (size_t)B_ * T_ * H_);               // 36 MB
    float* MLpart = (float*)((char*)Opart + (size_t)288 * 32768 * 4);   // 0.56 MB

    wconv_kernel<<<(384 * 1024) / 256, 256, 0, stream>>>(Wq, Wk, Wv, Wt);
    gemm_kernel<<<B_ * T_ / 64, 512, 0, stream>>>(x, Wt, qbf, kbf, vTf);
    attn1_kernel<<<512, 512, 0, stream>>>(qbf, kbf, vTf, Opart, MLpart);
    attn2_kernel<<<512, 128, 0, stream>>>(Opart, MLpart, out);
}